// Round 12
// baseline (702.582 us; speedup 1.0000x reference)
//
#include <hip/hip_runtime.h>
#include <math.h>

#define NPG    1024
#define KNN    20
#define NGRAPH 64
#define NTOT   (NGRAPH * NPG)   // 65536
#define HD     16
#define EPB    16               // nodes per edge-block
#define TPB    (EPB * KNN)      // 320 threads
#define SMSTR  17               // padded LDS row stride (conflict-free scalar)
#define PSTR   96               // per-node precompute row: u[32] v[32] n[32]

#define SCN    4                // knn scanners per node
#define NLB    128              // knn nodes per block

typedef float v2f __attribute__((ext_vector_type(2)));
typedef float v4f __attribute__((ext_vector_type(4)));

#define CSPACE __attribute__((address_space(4)))
__device__ __forceinline__ const CSPACE float* cptr(const float* p) {
    return (const CSPACE float*)(unsigned long long)p;
}
__device__ __forceinline__ const CSPACE v4f* c4(const float* p) {
    return (const CSPACE v4f*)(unsigned long long)p;
}

__device__ __forceinline__ float silu_f(float x) {
    float e = __expf(-x);
    return x * __fdividef(1.0f, 1.0f + e);
}
__device__ __forceinline__ v4f silu4(v4f x) {
#pragma unroll
    for (int k = 0; k < 4; ++k) {
        float a = x[k];
        x[k] = a * __fdividef(1.0f, 1.0f + __expf(-a));
    }
    return x;
}

__device__ __forceinline__ float d2_exact(float xi, float yi, float zi, float sqi,
                                          float xj, float yj, float zj, float sqj) {
    float dot = __fadd_rn(__fadd_rn(__fmul_rn(xi, xj), __fmul_rn(yi, yj)),
                          __fmul_rn(zi, zj));
    return __fsub_rn(__fadd_rn(sqi, sqj), __fmul_rn(2.0f, dot));
}

// ---------------------------------------------------------------------------
// KNN (unchanged — proven)
// ---------------------------------------------------------------------------
__global__ __launch_bounds__(512) void knn_kernel(const float* __restrict__ pos,
                                                  int* __restrict__ srcidx) {
    __shared__ float4 sp[NPG];
    __shared__ float  lists[SCN][NLB][21];
    __shared__ float  taus[NLB];
    __shared__ int    cnts[SCN][NLB];
    __shared__ int    tcnts[SCN][NLB];
    __shared__ int    ties[SCN][NLB][4];

    const int t     = threadIdx.x;
    const int g     = blockIdx.x >> 3;
    const int chunk = blockIdx.x & 7;
    const int base  = g * NPG;

    for (int u = t; u < NPG; u += 512) {
        float x = pos[(size_t)(base + u) * 3 + 0];
        float y = pos[(size_t)(base + u) * 3 + 1];
        float z = pos[(size_t)(base + u) * 3 + 2];
        float sq = __fadd_rn(__fadd_rn(__fmul_rn(x, x), __fmul_rn(y, y)),
                             __fmul_rn(z, z));
        sp[u] = make_float4(x, y, z, sq);
    }
    __syncthreads();

    const int nl = t & (NLB - 1);
    const int s  = t >> 7;
    const int li = chunk * NLB + nl;
    const float4 qi = sp[li];

    float sl[KNN];
#pragma unroll
    for (int p = 0; p < KNN; ++p) sl[p] = INFINITY;

    const int jbeg = s * 256, jend = jbeg + 256;
    for (int j0 = jbeg; j0 < jend; j0 += 4) {
        float4 qa = sp[j0 + 0];
        float4 qb = sp[j0 + 1];
        float4 qc = sp[j0 + 2];
        float4 qd = sp[j0 + 3];
        float d0 = d2_exact(qi.x, qi.y, qi.z, qi.w, qa.x, qa.y, qa.z, qa.w);
        float d1 = d2_exact(qi.x, qi.y, qi.z, qi.w, qb.x, qb.y, qb.z, qb.w);
        float d2 = d2_exact(qi.x, qi.y, qi.z, qi.w, qc.x, qc.y, qc.z, qc.w);
        float d3 = d2_exact(qi.x, qi.y, qi.z, qi.w, qd.x, qd.y, qd.z, qd.w);
        d0 = (j0 + 0 == li) ? INFINITY : d0;
        d1 = (j0 + 1 == li) ? INFINITY : d1;
        d2 = (j0 + 2 == li) ? INFINITY : d2;
        d3 = (j0 + 3 == li) ? INFINITY : d3;
        float dd[4] = {d0, d1, d2, d3};
#pragma unroll
        for (int u = 0; u < 4; ++u) {
            const float d = dd[u];
#pragma unroll
            for (int p = KNN - 1; p >= 1; --p)
                sl[p] = __builtin_amdgcn_fmed3f(sl[p - 1], d, sl[p]);
            sl[0] = fminf(sl[0], d);
        }
    }

#pragma unroll
    for (int p = 0; p < KNN; ++p) lists[s][nl][p] = sl[p];
    __syncthreads();

    if (s == 0) {
        int i0 = 0, i1 = 0, i2 = 0, i3 = 0;
        float h0 = lists[0][nl][0], h1 = lists[1][nl][0];
        float h2 = lists[2][nl][0], h3 = lists[3][nl][0];
        float cur = h0;
#pragma unroll
        for (int step = 0; step < KNN; ++step) {
            int which = 0; cur = h0;
            if (h1 < cur) { cur = h1; which = 1; }
            if (h2 < cur) { cur = h2; which = 2; }
            if (h3 < cur) { cur = h3; which = 3; }
            if (which == 0)      { ++i0; h0 = lists[0][nl][i0]; }
            else if (which == 1) { ++i1; h1 = lists[1][nl][i1]; }
            else if (which == 2) { ++i2; h2 = lists[2][nl][i2]; }
            else                 { ++i3; h3 = lists[3][nl][i3]; }
        }
        taus[nl] = cur;
    }
    __syncthreads();

    const float tau = taus[nl];
    const int outbase = (base + li) * KNN;

    int cnt = 0, tc = 0;
    int tj0 = 0, tj1 = 0, tj2 = 0, tj3 = 0;
#pragma unroll 4
    for (int j = jbeg; j < jend; ++j) {
        if (j == li) continue;
        float4 q = sp[j];
        float d = d2_exact(qi.x, qi.y, qi.z, qi.w, q.x, q.y, q.z, q.w);
        if (d < tau) ++cnt;
        else if (d == tau) {
            if (tc == 0) tj0 = j;
            else if (tc == 1) tj1 = j;
            else if (tc == 2) tj2 = j;
            else if (tc == 3) tj3 = j;
            ++tc;
        }
    }
    cnts[s][nl]  = cnt;
    tcnts[s][nl] = (tc < 4) ? tc : 4;
    ties[s][nl][0] = tj0; ties[s][nl][1] = tj1;
    ties[s][nl][2] = tj2; ties[s][nl][3] = tj3;
    __syncthreads();

    int w = outbase;
#pragma unroll
    for (int ss = 0; ss < SCN; ++ss) if (ss < s) w += cnts[ss][nl];
#pragma unroll 4
    for (int j = jbeg; j < jend; ++j) {
        if (j == li) continue;
        float4 q = sp[j];
        float d = d2_exact(qi.x, qi.y, qi.z, qi.w, q.x, q.y, q.z, q.w);
        if (d < tau) { srcidx[w] = base + j; ++w; }
    }

    if (s == 0) {
        int total = cnts[0][nl] + cnts[1][nl] + cnts[2][nl] + cnts[3][nl];
        int need = KNN - total;
        int w2 = outbase + total;
        for (int ss = 0; ss < SCN && need > 0; ++ss) {
            int tn = tcnts[ss][nl];
            for (int u = 0; u < tn && need > 0; ++u) {
                srcidx[w2] = base + ties[ss][nl][u];
                ++w2; --need;
            }
        }
    }
}

// ---------------------------------------------------------------------------
// embedding (unchanged)
// ---------------------------------------------------------------------------
__global__ __launch_bounds__(256) void embed_kernel(
    const float* __restrict__ pos,
    const float* __restrict__ w1_, const float* __restrict__ b1_,
    const float* __restrict__ w2_, const float* __restrict__ b2_,
    float* __restrict__ h) {
    const auto w1 = cptr(w1_); const auto b1 = cptr(b1_);
    const auto w2 = cptr(w2_); const auto b2 = cptr(b2_);
    const int i = blockIdx.x * 256 + threadIdx.x;
    if (i >= NTOT) return;
    const float x = pos[3 * (size_t)i + 0];
    const float y = pos[3 * (size_t)i + 1];
    const float z = pos[3 * (size_t)i + 2];

    float t[HD];
#pragma unroll
    for (int o = 0; o < HD; ++o)
        t[o] = silu_f(b1[o] + x * w1[0 * HD + o] + y * w1[1 * HD + o] + z * w1[2 * HD + o]);

    float r[HD];
#pragma unroll
    for (int o = 0; o < HD; ++o) r[o] = b2[o];
#pragma unroll
    for (int c = 0; c < HD; ++c) {
        const float a = t[c];
#pragma unroll
        for (int o = 0; o < HD; ++o) r[o] += a * w2[c * HD + o];
    }
    float4* hp = (float4*)(h + (size_t)i * HD);
    hp[0] = make_float4(r[0], r[1], r[2], r[3]);
    hp[1] = make_float4(r[4], r[5], r[6], r[7]);
    hp[2] = make_float4(r[8], r[9], r[10], r[11]);
    hp[3] = make_float4(r[12], r[13], r[14], r[15]);
}

// ---------------------------------------------------------------------------
// per-node, per-layer precompute (unchanged from R9)
// ---------------------------------------------------------------------------
__global__ __launch_bounds__(256) void pre_kernel(
    const float* __restrict__ h,
    const float* __restrict__ ew1_, const float* __restrict__ eb1_,
    const float* __restrict__ nw1_, const float* __restrict__ nb1_,
    float* __restrict__ pre) {
    const int m = blockIdx.x >> 8;                       // 0:u 1:v 2:n
    const int i = ((blockIdx.x & 255) << 8) + threadIdx.x;

    float hv[HD];
    {
        const float4* p = (const float4*)(h + (size_t)i * HD);
        float4 a = p[0], b = p[1], c = p[2], d = p[3];
        hv[0] = a.x; hv[1] = a.y; hv[2] = a.z; hv[3] = a.w;
        hv[4] = b.x; hv[5] = b.y; hv[6] = b.z; hv[7] = b.w;
        hv[8] = c.x; hv[9] = c.y; hv[10] = c.z; hv[11] = c.w;
        hv[12] = d.x; hv[13] = d.y; hv[14] = d.z; hv[15] = d.w;
    }

    const CSPACE v4f* W;
    v4f acc[8];
    if (m == 0) {
        W = c4(ew1_);
        const auto B = c4(eb1_);
#pragma unroll
        for (int og = 0; og < 8; ++og) acc[og] = B[og];
    } else if (m == 1) {
        W = c4(ew1_) + HD * 8;
#pragma unroll
        for (int og = 0; og < 8; ++og) acc[og] = (v4f){0.0f, 0.0f, 0.0f, 0.0f};
    } else {
        W = c4(nw1_);
        const auto B = c4(nb1_);
#pragma unroll
        for (int og = 0; og < 8; ++og) acc[og] = B[og];
    }

#pragma unroll
    for (int c = 0; c < HD; ++c) {
        const v4f av = {hv[c], hv[c], hv[c], hv[c]};
#pragma unroll
        for (int og = 0; og < 8; ++og)
            acc[og] += av * W[c * 8 + og];
    }

    v4f* out = (v4f*)(pre + (size_t)i * PSTR + 32 * m);
#pragma unroll
    for (int og = 0; og < 8; ++og) out[og] = acc[og];
}

// ---------------------------------------------------------------------------
// edge kernel (fission): edge MLP + single-barrier mean/max reduce only.
// ---------------------------------------------------------------------------
__global__ __launch_bounds__(TPB) void edge_kernel(
    const float* __restrict__ pos, const int* __restrict__ srcidx,
    const float* __restrict__ pre,
    const float* __restrict__ ew1_,
    const float* __restrict__ ew2_, const float* __restrict__ eb2_,
    const float* __restrict__ ew3_, const float* __restrict__ eb3_,
    float* __restrict__ gbuf) {
    __shared__ float sm[TPB * SMSTR];   // 21.76 KB

    const auto W1g = c4(ew1_) + 32 * 8;          // geo rows 32..36
    const auto W2  = c4(ew2_); const auto B2 = c4(eb2_);
    const auto W3  = c4(ew3_); const auto B3 = c4(eb3_);

    const int t = threadIdx.x;
    const int e = blockIdx.x * TPB + t;
    const int i = e / KNN;
    const int j = srcidx[e];

    const float pix = pos[3 * (size_t)i + 0];
    const float piy = pos[3 * (size_t)i + 1];
    const float piz = pos[3 * (size_t)i + 2];
    const float pjx = pos[3 * (size_t)j + 0];
    const float pjy = pos[3 * (size_t)j + 1];
    const float pjz = pos[3 * (size_t)j + 2];

    const float rx = pjx - pix, ry = pjy - piy, rz = pjz - piz;
    const float dist = sqrtf(rx * rx + ry * ry + rz * rz);
    const float rid  = __fdividef(1.0f, dist + 1e-8f);
    const float dirx = rx * rid, diry = ry * rid, dirz = rz * rid;
    const float ni  = sqrtf(pix * pix + piy * piy + piz * piz);
    const float rni = __fdividef(1.0f, ni + 1e-8f);
    const float nj  = sqrtf(pjx * pjx + pjy * pjy + pjz * pjz);
    const float rnj = __fdividef(1.0f, nj + 1e-8f);
    const float dotf = (pix * rni) * (pjx * rnj) + (piy * rni) * (pjy * rnj)
                     + (piz * rni) * (pjz * rnj);

    // layer 1: t1 = u_i + v_j + geo @ W1g
    const CSPACE v4f* ui = c4(pre) + (size_t)i * (PSTR / 4);
    const CSPACE v4f* vj = c4(pre) + (size_t)j * (PSTR / 4) + 8;
    v4f t1[8];
#pragma unroll
    for (int og = 0; og < 8; ++og) t1[og] = ui[og] + vj[og];
    {
        const float gg[5] = {dist, dirx, diry, dirz, dotf};
#pragma unroll
        for (int r = 0; r < 5; ++r) {
            const v4f gv = {gg[r], gg[r], gg[r], gg[r]};
#pragma unroll
            for (int og = 0; og < 8; ++og)
                t1[og] += gv * W1g[r * 8 + og];
        }
    }
#pragma unroll
    for (int og = 0; og < 8; ++og) t1[og] = silu4(t1[og]);

    // layer 2
    v4f t2[4];
#pragma unroll
    for (int og = 0; og < 4; ++og) t2[og] = B2[og];
#pragma unroll
    for (int c = 0; c < 32; ++c) {
        const float a = t1[c >> 2][c & 3];
        const v4f av = {a, a, a, a};
#pragma unroll
        for (int og = 0; og < 4; ++og)
            t2[og] += av * W2[c * 4 + og];
    }
#pragma unroll
    for (int og = 0; og < 4; ++og) t2[og] = silu4(t2[og]);

    // layer 3 -> message in sm
    v4f mv[4];
#pragma unroll
    for (int og = 0; og < 4; ++og) mv[og] = B3[og];
#pragma unroll
    for (int c = 0; c < HD; ++c) {
        const float a = t2[c >> 2][c & 3];
        const v4f av = {a, a, a, a};
#pragma unroll
        for (int og = 0; og < 4; ++og)
            mv[og] += av * W3[c * 4 + og];
    }
#pragma unroll
    for (int og = 0; og < 4; ++og) {
        sm[t * SMSTR + 4 * og + 0] = mv[og][0];
        sm[t * SMSTR + 4 * og + 1] = mv[og][1];
        sm[t * SMSTR + 4 * og + 2] = mv[og][2];
        sm[t * SMSTR + 4 * og + 3] = mv[og][3];
    }

    __syncthreads();

    // reduce: thread (n,o) -> mean/max of node n feature o, write gbuf
    if (t < 256) {
        const int n = t >> 4;
        const int o = t & 15;
        float redsum = 0.0f, redmax = -INFINITY;
#pragma unroll
        for (int k = 0; k < KNN; ++k) {
            float v = sm[(n * KNN + k) * SMSTR + o];
            redsum += v;
            redmax = fmaxf(redmax, v);
        }
        const int gnode = blockIdx.x * EPB + n;
        gbuf[(size_t)gnode * 32 + o]      = redsum / 20.0f;
        gbuf[(size_t)gnode * 32 + 16 + o] = redmax;
    }
}

// ---------------------------------------------------------------------------
// node kernel (fission): node MLP + residual. 256 threads = 16 nodes.
// GRID MUST BE NTOT/EPB = 4096 blocks (R10 bug: launched 256).
// ---------------------------------------------------------------------------
__global__ __launch_bounds__(256) void node_kernel(
    const float* __restrict__ h_in, const float* __restrict__ gbuf,
    const float* __restrict__ pre,
    const float* __restrict__ nw1_,
    const float* __restrict__ nw2_, const float* __restrict__ nb2_,
    float* __restrict__ h_out) {
    __shared__ float n1s[32 * 32];   // nw1 rows 16..47 (mean,max parts)
    __shared__ float n2s[32 * HD];
    __shared__ float nb2s[HD];
    __shared__ float mm[EPB * 32];   // [n][me(16) mx(16)]
    __shared__ float u1s[EPB * 40];

    const int t = threadIdx.x;

    for (int u = t; u < 32 * 32; u += 256) n1s[u] = nw1_[512 + u];
    for (int u = t; u < 32 * HD; u += 256) n2s[u] = nw2_[u];
    if (t < HD) nb2s[t] = nb2_[t];
    for (int u = t; u < EPB * 32; u += 256)
        mm[u] = gbuf[(size_t)blockIdx.x * EPB * 32 + u];

    const float hi_no = h_in[(size_t)blockIdx.x * 256 + t];

    __syncthreads();

    const int n = t >> 4;
    const int o = t & 15;
    const int gnode = blockIdx.x * EPB + n;

    float o0 = pre[(size_t)gnode * PSTR + 64 + o];
    float o1 = pre[(size_t)gnode * PSTR + 80 + o];
#pragma unroll
    for (int c = 0; c < HD; ++c) {
        const float mc = mm[n * 32 + c];
        const float xc = mm[n * 32 + 16 + c];
        o0 += mc * n1s[c * 32 + o]      + xc * n1s[(HD + c) * 32 + o];
        o1 += mc * n1s[c * 32 + o + 16] + xc * n1s[(HD + c) * 32 + o + 16];
    }
    u1s[n * 40 + o]      = silu_f(o0);
    u1s[n * 40 + o + 16] = silu_f(o1);

    __syncthreads();

    float acc = nb2s[o];
#pragma unroll
    for (int c = 0; c < 32; ++c) acc += u1s[n * 40 + c] * n2s[c * HD + o];
    h_out[(size_t)blockIdx.x * 256 + t] = hi_no + acc;
}

// ---------------------------------------------------------------------------
// output head (unchanged)
// ---------------------------------------------------------------------------
__global__ __launch_bounds__(256) void out_kernel(
    const float* __restrict__ h,
    const float* __restrict__ ow1_, const float* __restrict__ ob1_,
    const float* __restrict__ ow2_, const float* __restrict__ ob2_,
    const float* __restrict__ ow3_, const float* __restrict__ ob3_,
    float* __restrict__ out) {
    const auto ow1 = cptr(ow1_); const auto ob1 = cptr(ob1_);
    const auto ow2 = cptr(ow2_); const auto ob2 = cptr(ob2_);
    const auto ow3 = cptr(ow3_); const auto ob3 = cptr(ob3_);
    const int i = blockIdx.x * 256 + threadIdx.x;
    if (i >= NTOT) return;

    float hv[HD];
    {
        const float4* p = (const float4*)(h + (size_t)i * HD);
        float4 a = p[0], b = p[1], c = p[2], d = p[3];
        hv[0] = a.x; hv[1] = a.y; hv[2] = a.z; hv[3] = a.w;
        hv[4] = b.x; hv[5] = b.y; hv[6] = b.z; hv[7] = b.w;
        hv[8] = c.x; hv[9] = c.y; hv[10] = c.z; hv[11] = c.w;
        hv[12] = d.x; hv[13] = d.y; hv[14] = d.z; hv[15] = d.w;
    }

    float t1[HD];
#pragma unroll
    for (int o = 0; o < HD; ++o) t1[o] = ob1[o];
#pragma unroll
    for (int c = 0; c < HD; ++c) {
        const float a = hv[c];
#pragma unroll
        for (int o = 0; o < HD; ++o) t1[o] += a * ow1[c * HD + o];
    }
#pragma unroll
    for (int o = 0; o < HD; ++o) t1[o] = silu_f(t1[o]);

    float t2[8];
#pragma unroll
    for (int o = 0; o < 8; ++o) t2[o] = ob2[o];
#pragma unroll
    for (int c = 0; c < HD; ++c) {
        const float a = t1[c];
#pragma unroll
        for (int o = 0; o < 8; ++o) t2[o] += a * ow2[c * 8 + o];
    }
#pragma unroll
    for (int o = 0; o < 8; ++o) t2[o] = silu_f(t2[o]);

    float r0 = ob3[0], r1 = ob3[1], r2 = ob3[2];
#pragma unroll
    for (int c = 0; c < 8; ++c) {
        r0 += t2[c] * ow3[c * 3 + 0];
        r1 += t2[c] * ow3[c * 3 + 1];
        r2 += t2[c] * ow3[c * 3 + 2];
    }
    out[3 * (size_t)i + 0] = r0;
    out[3 * (size_t)i + 1] = r1;
    out[3 * (size_t)i + 2] = r2;
}

// ---------------------------------------------------------------------------
extern "C" void kernel_launch(void* const* d_in, const int* in_sizes, int n_in,
                              void* d_out, int out_size, void* d_ws, size_t ws_size,
                              hipStream_t stream) {
    const float* pos   = (const float*)d_in[0];
    const float* pe_w1 = (const float*)d_in[1];
    const float* pe_b1 = (const float*)d_in[2];
    const float* pe_w2 = (const float*)d_in[3];
    const float* pe_b2 = (const float*)d_in[4];
    const float* ew1   = (const float*)d_in[5];
    const float* eb1   = (const float*)d_in[6];
    const float* ew2   = (const float*)d_in[7];
    const float* eb2   = (const float*)d_in[8];
    const float* ew3   = (const float*)d_in[9];
    const float* eb3   = (const float*)d_in[10];
    const float* nw1   = (const float*)d_in[11];
    const float* nb1   = (const float*)d_in[12];
    const float* nw2   = (const float*)d_in[13];
    const float* nb2   = (const float*)d_in[14];
    const float* ow1   = (const float*)d_in[15];
    const float* ob1   = (const float*)d_in[16];
    const float* ow2   = (const float*)d_in[17];
    const float* ob2   = (const float*)d_in[18];
    const float* ow3   = (const float*)d_in[19];
    const float* ob3   = (const float*)d_in[20];

    char* ws = (char*)d_ws;
    int*   srcidx = (int*)ws;                                      // 5.24 MB
    float* h0   = (float*)(ws + (size_t)NTOT * KNN * sizeof(int)); // 4.19 MB
    float* h1   = h0 + (size_t)NTOT * HD;                          // 4.19 MB
    float* pre  = h1 + (size_t)NTOT * HD;                          // 25.2 MB
    float* gbuf = pre + (size_t)NTOT * PSTR;                       // 8.39 MB

    knn_kernel<<<NGRAPH * 8, 512, 0, stream>>>(pos, srcidx);
    embed_kernel<<<NTOT / 256, 256, 0, stream>>>(pos, pe_w1, pe_b1, pe_w2, pe_b2, h0);

    const int eblocks = (NTOT * KNN) / TPB;   // 4096
    for (int l = 0; l < 4; ++l) {
        const float* hin  = (l & 1) ? h1 : h0;
        float*       hout = (l & 1) ? h0 : h1;
        const float* ew1l = ew1 + (size_t)l * 37 * 32;
        const float* eb1l = eb1 + (size_t)l * 32;
        const float* nw1l = nw1 + (size_t)l * 48 * 32;
        const float* nb1l = nb1 + (size_t)l * 32;
        pre_kernel<<<768, 256, 0, stream>>>(hin, ew1l, eb1l, nw1l, nb1l, pre);
        edge_kernel<<<eblocks, TPB, 0, stream>>>(
            pos, srcidx, pre, ew1l,
            ew2 + (size_t)l * 32 * 16, eb2 + (size_t)l * 16,
            ew3 + (size_t)l * 16 * 16, eb3 + (size_t)l * 16,
            gbuf);
        node_kernel<<<NTOT / EPB, 256, 0, stream>>>(   // 4096 blocks (R10 bug fixed)
            hin, gbuf, pre, nw1l,
            nw2 + (size_t)l * 32 * 16, nb2 + (size_t)l * 16,
            hout);
    }

    out_kernel<<<NTOT / 256, 256, 0, stream>>>(h0, ow1, ob1, ow2, ob2, ow3, ob3,
                                               (float*)d_out);
}

// Round 13
// 658.812 us; speedup vs baseline: 1.0664x; 1.0664x over previous
//
#include <hip/hip_runtime.h>
#include <math.h>

#define NPG    1024
#define KNN    20
#define NGRAPH 64
#define NTOT   (NGRAPH * NPG)   // 65536
#define HD     16
#define EPB    16               // nodes per edge-block
#define TPB    (EPB * KNN)      // 320 threads
#define SMSTR  17               // padded LDS row stride
#define PSTR   96               // per-node precompute row: u[32] v[32] n[32]

#define SCN    4                // knn scanners per node
#define NLB    128              // knn nodes per block

typedef float v4f __attribute__((ext_vector_type(4)));

#define CSPACE __attribute__((address_space(4)))
__device__ __forceinline__ const CSPACE float* cptr(const float* p) {
    return (const CSPACE float*)(unsigned long long)p;
}
__device__ __forceinline__ const CSPACE v4f* c4(const float* p) {
    return (const CSPACE v4f*)(unsigned long long)p;
}

__device__ __forceinline__ float silu_f(float x) {
    float e = __expf(-x);
    return x * __fdividef(1.0f, 1.0f + e);
}
__device__ __forceinline__ v4f silu4(v4f x) {
#pragma unroll
    for (int k = 0; k < 4; ++k) {
        float a = x[k];
        x[k] = a * __fdividef(1.0f, 1.0f + __expf(-a));
    }
    return x;
}

__device__ __forceinline__ float d2_exact(float xi, float yi, float zi, float sqi,
                                          float xj, float yj, float zj, float sqj) {
    float dot = __fadd_rn(__fadd_rn(__fmul_rn(xi, xj), __fmul_rn(yi, yj)),
                          __fmul_rn(zi, zj));
    return __fsub_rn(__fadd_rn(sqi, sqj), __fmul_rn(2.0f, dot));
}

// ---------------------------------------------------------------------------
// KNN v4: pass-2 fused to a single scan. Winners staged in LDS (aliasing the
// dead `lists` array), each scanner copies its run at its prefix offset;
// ties filled by scanner 0 ascending (scanner ranges ascend in j).
// ---------------------------------------------------------------------------
__global__ __launch_bounds__(512) void knn_kernel(const float* __restrict__ pos,
                                                  int* __restrict__ srcidx) {
    __shared__ float4 sp[NPG];
    __shared__ float  lists[SCN][NLB][21];   // pass1 lists; aliased as stage in pass2
    __shared__ float  taus[NLB];
    __shared__ int    cnts[SCN][NLB];
    __shared__ int    tcnts[SCN][NLB];
    __shared__ int    ties[SCN][NLB][4];

    const int t     = threadIdx.x;
    const int g     = blockIdx.x >> 3;
    const int chunk = blockIdx.x & 7;
    const int base  = g * NPG;

    for (int u = t; u < NPG; u += 512) {
        float x = pos[(size_t)(base + u) * 3 + 0];
        float y = pos[(size_t)(base + u) * 3 + 1];
        float z = pos[(size_t)(base + u) * 3 + 2];
        float sq = __fadd_rn(__fadd_rn(__fmul_rn(x, x), __fmul_rn(y, y)),
                             __fmul_rn(z, z));
        sp[u] = make_float4(x, y, z, sq);
    }
    __syncthreads();

    const int nl = t & (NLB - 1);
    const int s  = t >> 7;
    const int li = chunk * NLB + nl;
    const float4 qi = sp[li];

    float sl[KNN];
#pragma unroll
    for (int p = 0; p < KNN; ++p) sl[p] = INFINITY;

    const int jbeg = s * 256, jend = jbeg + 256;
    for (int j0 = jbeg; j0 < jend; j0 += 4) {
        float4 qa = sp[j0 + 0];
        float4 qb = sp[j0 + 1];
        float4 qc = sp[j0 + 2];
        float4 qd = sp[j0 + 3];
        float d0 = d2_exact(qi.x, qi.y, qi.z, qi.w, qa.x, qa.y, qa.z, qa.w);
        float d1 = d2_exact(qi.x, qi.y, qi.z, qi.w, qb.x, qb.y, qb.z, qb.w);
        float d2 = d2_exact(qi.x, qi.y, qi.z, qi.w, qc.x, qc.y, qc.z, qc.w);
        float d3 = d2_exact(qi.x, qi.y, qi.z, qi.w, qd.x, qd.y, qd.z, qd.w);
        d0 = (j0 + 0 == li) ? INFINITY : d0;
        d1 = (j0 + 1 == li) ? INFINITY : d1;
        d2 = (j0 + 2 == li) ? INFINITY : d2;
        d3 = (j0 + 3 == li) ? INFINITY : d3;
        float dd[4] = {d0, d1, d2, d3};
#pragma unroll
        for (int u = 0; u < 4; ++u) {
            const float d = dd[u];
#pragma unroll
            for (int p = KNN - 1; p >= 1; --p)
                sl[p] = __builtin_amdgcn_fmed3f(sl[p - 1], d, sl[p]);
            sl[0] = fminf(sl[0], d);
        }
    }

#pragma unroll
    for (int p = 0; p < KNN; ++p) lists[s][nl][p] = sl[p];
    __syncthreads();

    if (s == 0) {
        int i0 = 0, i1 = 0, i2 = 0, i3 = 0;
        float h0 = lists[0][nl][0], h1 = lists[1][nl][0];
        float h2 = lists[2][nl][0], h3 = lists[3][nl][0];
        float cur = h0;
#pragma unroll
        for (int step = 0; step < KNN; ++step) {
            int which = 0; cur = h0;
            if (h1 < cur) { cur = h1; which = 1; }
            if (h2 < cur) { cur = h2; which = 2; }
            if (h3 < cur) { cur = h3; which = 3; }
            if (which == 0)      { ++i0; h0 = lists[0][nl][i0]; }
            else if (which == 1) { ++i1; h1 = lists[1][nl][i1]; }
            else if (which == 2) { ++i2; h2 = lists[2][nl][i2]; }
            else                 { ++i3; h3 = lists[3][nl][i3]; }
        }
        taus[nl] = cur;
    }
    __syncthreads();   // merges done -> lists dead, safe to alias as stage

    const float tau = taus[nl];
    const int outbase = (base + li) * KNN;
    int* stage = ((int*)lists) + (s * NLB + nl) * 21;   // <=19 winners fit

    // single fused scan: stage winners, collect ties
    int cnt = 0, tc = 0;
    int tj0 = 0, tj1 = 0, tj2 = 0, tj3 = 0;
#pragma unroll 4
    for (int j = jbeg; j < jend; ++j) {
        if (j == li) continue;
        float4 q = sp[j];
        float d = d2_exact(qi.x, qi.y, qi.z, qi.w, q.x, q.y, q.z, q.w);
        if (d < tau) { stage[cnt] = base + j; ++cnt; }
        else if (d == tau) {
            if (tc == 0) tj0 = j;
            else if (tc == 1) tj1 = j;
            else if (tc == 2) tj2 = j;
            else if (tc == 3) tj3 = j;
            ++tc;
        }
    }
    cnts[s][nl]  = cnt;
    tcnts[s][nl] = (tc < 4) ? tc : 4;
    ties[s][nl][0] = tj0; ties[s][nl][1] = tj1;
    ties[s][nl][2] = tj2; ties[s][nl][3] = tj3;
    __syncthreads();

    // each scanner copies its staged run at its prefix offset (ascending j)
    int w = outbase;
#pragma unroll
    for (int ss = 0; ss < SCN; ++ss) if (ss < s) w += cnts[ss][nl];
    for (int k = 0; k < cnt; ++k) srcidx[w + k] = stage[k];

    if (s == 0) {
        int total = cnts[0][nl] + cnts[1][nl] + cnts[2][nl] + cnts[3][nl];
        int need = KNN - total;
        int w2 = outbase + total;
        for (int ss = 0; ss < SCN && need > 0; ++ss) {
            int tn = tcnts[ss][nl];
            for (int u = 0; u < tn && need > 0; ++u) {
                srcidx[w2] = base + ties[ss][nl][u];
                ++w2; --need;
            }
        }
    }
}

// ---------------------------------------------------------------------------
// embedding + layer-0 pre fold: h = MLP(pos); pre[i] = {u,v,n} for layer 0.
// Same v4f accumulation order as the old pre_kernel (bit-exact).
// ---------------------------------------------------------------------------
__global__ __launch_bounds__(256) void embed_kernel(
    const float* __restrict__ pos,
    const float* __restrict__ w1_, const float* __restrict__ b1_,
    const float* __restrict__ w2_, const float* __restrict__ b2_,
    const float* __restrict__ ew1_, const float* __restrict__ eb1_,
    const float* __restrict__ nw1_, const float* __restrict__ nb1_,
    float* __restrict__ h, float* __restrict__ pre) {
    const auto w1 = cptr(w1_); const auto b1 = cptr(b1_);
    const auto w2 = cptr(w2_); const auto b2 = cptr(b2_);
    const int i = blockIdx.x * 256 + threadIdx.x;
    if (i >= NTOT) return;
    const float x = pos[3 * (size_t)i + 0];
    const float y = pos[3 * (size_t)i + 1];
    const float z = pos[3 * (size_t)i + 2];

    float tt[HD];
#pragma unroll
    for (int o = 0; o < HD; ++o)
        tt[o] = silu_f(b1[o] + x * w1[0 * HD + o] + y * w1[1 * HD + o] + z * w1[2 * HD + o]);

    float r[HD];
#pragma unroll
    for (int o = 0; o < HD; ++o) r[o] = b2[o];
#pragma unroll
    for (int c = 0; c < HD; ++c) {
        const float a = tt[c];
#pragma unroll
        for (int o = 0; o < HD; ++o) r[o] += a * w2[c * HD + o];
    }
    float4* hp = (float4*)(h + (size_t)i * HD);
    hp[0] = make_float4(r[0], r[1], r[2], r[3]);
    hp[1] = make_float4(r[4], r[5], r[6], r[7]);
    hp[2] = make_float4(r[8], r[9], r[10], r[11]);
    hp[3] = make_float4(r[12], r[13], r[14], r[15]);

    // ---- fold: layer-0 pre (u, v, n), same order as old pre_kernel ----
    {
        const auto WU = c4(ew1_);            // rows 0..15
        const auto WV = c4(ew1_) + HD * 8;   // rows 16..31
        const auto WN = c4(nw1_);            // rows 0..15
        const auto BU = c4(eb1_);
        const auto BN = c4(nb1_);
        v4f au[8], av[8], an[8];
#pragma unroll
        for (int og = 0; og < 8; ++og) {
            au[og] = BU[og];
            av[og] = (v4f){0.0f, 0.0f, 0.0f, 0.0f};
            an[og] = BN[og];
        }
#pragma unroll
        for (int c = 0; c < HD; ++c) {
            const v4f hc = {r[c], r[c], r[c], r[c]};
#pragma unroll
            for (int og = 0; og < 8; ++og) {
                au[og] += hc * WU[c * 8 + og];
                av[og] += hc * WV[c * 8 + og];
                an[og] += hc * WN[c * 8 + og];
            }
        }
        v4f* out = (v4f*)(pre + (size_t)i * PSTR);
#pragma unroll
        for (int og = 0; og < 8; ++og) {
            out[og]      = au[og];
            out[8 + og]  = av[og];
            out[16 + og] = an[og];
        }
    }
}

// ---------------------------------------------------------------------------
// edge kernel (unchanged from R11 — proven): edge MLP + mean/max reduce.
// ---------------------------------------------------------------------------
__global__ __launch_bounds__(TPB) void edge_kernel(
    const float* __restrict__ pos, const int* __restrict__ srcidx,
    const float* __restrict__ pre,
    const float* __restrict__ ew1_,
    const float* __restrict__ ew2_, const float* __restrict__ eb2_,
    const float* __restrict__ ew3_, const float* __restrict__ eb3_,
    float* __restrict__ gbuf) {
    __shared__ float sm[TPB * SMSTR];   // 21.76 KB

    const auto W1g = c4(ew1_) + 32 * 8;
    const auto W2  = c4(ew2_); const auto B2 = c4(eb2_);
    const auto W3  = c4(ew3_); const auto B3 = c4(eb3_);

    const int t = threadIdx.x;
    const int e = blockIdx.x * TPB + t;
    const int i = e / KNN;
    const int j = srcidx[e];

    const float pix = pos[3 * (size_t)i + 0];
    const float piy = pos[3 * (size_t)i + 1];
    const float piz = pos[3 * (size_t)i + 2];
    const float pjx = pos[3 * (size_t)j + 0];
    const float pjy = pos[3 * (size_t)j + 1];
    const float pjz = pos[3 * (size_t)j + 2];

    const float rx = pjx - pix, ry = pjy - piy, rz = pjz - piz;
    const float dist = sqrtf(rx * rx + ry * ry + rz * rz);
    const float rid  = __fdividef(1.0f, dist + 1e-8f);
    const float dirx = rx * rid, diry = ry * rid, dirz = rz * rid;
    const float ni  = sqrtf(pix * pix + piy * piy + piz * piz);
    const float rni = __fdividef(1.0f, ni + 1e-8f);
    const float nj  = sqrtf(pjx * pjx + pjy * pjy + pjz * pjz);
    const float rnj = __fdividef(1.0f, nj + 1e-8f);
    const float dotf = (pix * rni) * (pjx * rnj) + (piy * rni) * (pjy * rnj)
                     + (piz * rni) * (pjz * rnj);

    const CSPACE v4f* ui = c4(pre) + (size_t)i * (PSTR / 4);
    const CSPACE v4f* vj = c4(pre) + (size_t)j * (PSTR / 4) + 8;
    v4f t1[8];
#pragma unroll
    for (int og = 0; og < 8; ++og) t1[og] = ui[og] + vj[og];
    {
        const float gg[5] = {dist, dirx, diry, dirz, dotf};
#pragma unroll
        for (int r = 0; r < 5; ++r) {
            const v4f gv = {gg[r], gg[r], gg[r], gg[r]};
#pragma unroll
            for (int og = 0; og < 8; ++og)
                t1[og] += gv * W1g[r * 8 + og];
        }
    }
#pragma unroll
    for (int og = 0; og < 8; ++og) t1[og] = silu4(t1[og]);

    v4f t2[4];
#pragma unroll
    for (int og = 0; og < 4; ++og) t2[og] = B2[og];
#pragma unroll
    for (int c = 0; c < 32; ++c) {
        const float a = t1[c >> 2][c & 3];
        const v4f av = {a, a, a, a};
#pragma unroll
        for (int og = 0; og < 4; ++og)
            t2[og] += av * W2[c * 4 + og];
    }
#pragma unroll
    for (int og = 0; og < 4; ++og) t2[og] = silu4(t2[og]);

    v4f mv[4];
#pragma unroll
    for (int og = 0; og < 4; ++og) mv[og] = B3[og];
#pragma unroll
    for (int c = 0; c < HD; ++c) {
        const float a = t2[c >> 2][c & 3];
        const v4f av = {a, a, a, a};
#pragma unroll
        for (int og = 0; og < 4; ++og)
            mv[og] += av * W3[c * 4 + og];
    }
#pragma unroll
    for (int og = 0; og < 4; ++og) {
        sm[t * SMSTR + 4 * og + 0] = mv[og][0];
        sm[t * SMSTR + 4 * og + 1] = mv[og][1];
        sm[t * SMSTR + 4 * og + 2] = mv[og][2];
        sm[t * SMSTR + 4 * og + 3] = mv[og][3];
    }

    __syncthreads();

    if (t < 256) {
        const int n = t >> 4;
        const int o = t & 15;
        float redsum = 0.0f, redmax = -INFINITY;
#pragma unroll
        for (int k = 0; k < KNN; ++k) {
            float v = sm[(n * KNN + k) * SMSTR + o];
            redsum += v;
            redmax = fmaxf(redmax, v);
        }
        const int gnode = blockIdx.x * EPB + n;
        gbuf[(size_t)gnode * 32 + o]      = redsum / 20.0f;
        gbuf[(size_t)gnode * 32 + 16 + o] = redmax;
    }
}

// ---------------------------------------------------------------------------
// node kernel + next-layer pre fold. 256 threads = 16 nodes. Grid = NTOT/16.
// ---------------------------------------------------------------------------
__global__ __launch_bounds__(256) void node_kernel(
    const float* __restrict__ h_in, const float* __restrict__ gbuf,
    float* __restrict__ pre,
    const float* __restrict__ nw1_,
    const float* __restrict__ nw2_, const float* __restrict__ nb2_,
    float* __restrict__ h_out,
    const float* __restrict__ ew1n_, const float* __restrict__ eb1n_,
    const float* __restrict__ nw1n_, const float* __restrict__ nb1n_,
    int has_next) {
    __shared__ float n1s[32 * 32];   // nw1 rows 16..47 (mean,max)
    __shared__ float n2s[32 * HD];
    __shared__ float nb2s[HD];
    __shared__ float mm[EPB * 32];
    __shared__ float u1s[EPB * 40];
    __shared__ float uw[16 * 32];    // next ew1 rows 0..15
    __shared__ float vw[16 * 32];    // next ew1 rows 16..31
    __shared__ float nnw[16 * 32];   // next nw1 rows 0..15
    __shared__ float ubias[32], nbias[32];
    __shared__ float hns[EPB * 16];

    const int t = threadIdx.x;

    for (int u = t; u < 32 * 32; u += 256) n1s[u] = nw1_[512 + u];
    for (int u = t; u < 32 * HD; u += 256) n2s[u] = nw2_[u];
    if (t < HD) nb2s[t] = nb2_[t];
    for (int u = t; u < EPB * 32; u += 256)
        mm[u] = gbuf[(size_t)blockIdx.x * EPB * 32 + u];
    if (has_next) {
        for (int u = t; u < 512; u += 256) {
            uw[u]  = ew1n_[u];
            vw[u]  = ew1n_[512 + u];
            nnw[u] = nw1n_[u];
        }
        if (t < 32) { ubias[t] = eb1n_[t]; nbias[t] = nb1n_[t]; }
    }

    const float hi_no = h_in[(size_t)blockIdx.x * 256 + t];

    __syncthreads();

    const int n = t >> 4;
    const int o = t & 15;
    const int gnode = blockIdx.x * EPB + n;

    float o0 = pre[(size_t)gnode * PSTR + 64 + o];
    float o1 = pre[(size_t)gnode * PSTR + 80 + o];
#pragma unroll
    for (int c = 0; c < HD; ++c) {
        const float mc = mm[n * 32 + c];
        const float xc = mm[n * 32 + 16 + c];
        o0 += mc * n1s[c * 32 + o]      + xc * n1s[(HD + c) * 32 + o];
        o1 += mc * n1s[c * 32 + o + 16] + xc * n1s[(HD + c) * 32 + o + 16];
    }
    u1s[n * 40 + o]      = silu_f(o0);
    u1s[n * 40 + o + 16] = silu_f(o1);

    __syncthreads();

    float acc = nb2s[o];
#pragma unroll
    for (int c = 0; c < 32; ++c) acc += u1s[n * 40 + c] * n2s[c * HD + o];
    const float hnew = hi_no + acc;
    h_out[(size_t)blockIdx.x * 256 + t] = hnew;

    if (has_next) {
        hns[t] = hnew;
        __syncthreads();

        float uo0 = ubias[o], uo1 = ubias[o + 16];
        float vo0 = 0.0f,     vo1 = 0.0f;
        float no0 = nbias[o], no1 = nbias[o + 16];
#pragma unroll
        for (int c = 0; c < HD; ++c) {
            const float hc = hns[n * 16 + c];
            uo0 += hc * uw[c * 32 + o];   uo1 += hc * uw[c * 32 + o + 16];
            vo0 += hc * vw[c * 32 + o];   vo1 += hc * vw[c * 32 + o + 16];
            no0 += hc * nnw[c * 32 + o];  no1 += hc * nnw[c * 32 + o + 16];
        }
        float* pr = pre + (size_t)gnode * PSTR;
        pr[o]      = uo0;  pr[o + 16] = uo1;
        pr[32 + o] = vo0;  pr[48 + o] = vo1;
        pr[64 + o] = no0;  pr[80 + o] = no1;
    }
}

// ---------------------------------------------------------------------------
// output head (unchanged)
// ---------------------------------------------------------------------------
__global__ __launch_bounds__(256) void out_kernel(
    const float* __restrict__ h,
    const float* __restrict__ ow1_, const float* __restrict__ ob1_,
    const float* __restrict__ ow2_, const float* __restrict__ ob2_,
    const float* __restrict__ ow3_, const float* __restrict__ ob3_,
    float* __restrict__ out) {
    const auto ow1 = cptr(ow1_); const auto ob1 = cptr(ob1_);
    const auto ow2 = cptr(ow2_); const auto ob2 = cptr(ob2_);
    const auto ow3 = cptr(ow3_); const auto ob3 = cptr(ob3_);
    const int i = blockIdx.x * 256 + threadIdx.x;
    if (i >= NTOT) return;

    float hv[HD];
    {
        const float4* p = (const float4*)(h + (size_t)i * HD);
        float4 a = p[0], b = p[1], c = p[2], d = p[3];
        hv[0] = a.x; hv[1] = a.y; hv[2] = a.z; hv[3] = a.w;
        hv[4] = b.x; hv[5] = b.y; hv[6] = b.z; hv[7] = b.w;
        hv[8] = c.x; hv[9] = c.y; hv[10] = c.z; hv[11] = c.w;
        hv[12] = d.x; hv[13] = d.y; hv[14] = d.z; hv[15] = d.w;
    }

    float t1[HD];
#pragma unroll
    for (int o = 0; o < HD; ++o) t1[o] = ob1[o];
#pragma unroll
    for (int c = 0; c < HD; ++c) {
        const float a = hv[c];
#pragma unroll
        for (int o = 0; o < HD; ++o) t1[o] += a * ow1[c * HD + o];
    }
#pragma unroll
    for (int o = 0; o < HD; ++o) t1[o] = silu_f(t1[o]);

    float t2[8];
#pragma unroll
    for (int o = 0; o < 8; ++o) t2[o] = ob2[o];
#pragma unroll
    for (int c = 0; c < HD; ++c) {
        const float a = t1[c];
#pragma unroll
        for (int o = 0; o < 8; ++o) t2[o] += a * ow2[c * 8 + o];
    }
#pragma unroll
    for (int o = 0; o < 8; ++o) t2[o] = silu_f(t2[o]);

    float r0 = ob3[0], r1 = ob3[1], r2 = ob3[2];
#pragma unroll
    for (int c = 0; c < 8; ++c) {
        r0 += t2[c] * ow3[c * 3 + 0];
        r1 += t2[c] * ow3[c * 3 + 1];
        r2 += t2[c] * ow3[c * 3 + 2];
    }
    out[3 * (size_t)i + 0] = r0;
    out[3 * (size_t)i + 1] = r1;
    out[3 * (size_t)i + 2] = r2;
}

// ---------------------------------------------------------------------------
extern "C" void kernel_launch(void* const* d_in, const int* in_sizes, int n_in,
                              void* d_out, int out_size, void* d_ws, size_t ws_size,
                              hipStream_t stream) {
    const float* pos   = (const float*)d_in[0];
    const float* pe_w1 = (const float*)d_in[1];
    const float* pe_b1 = (const float*)d_in[2];
    const float* pe_w2 = (const float*)d_in[3];
    const float* pe_b2 = (const float*)d_in[4];
    const float* ew1   = (const float*)d_in[5];
    const float* eb1   = (const float*)d_in[6];
    const float* ew2   = (const float*)d_in[7];
    const float* eb2   = (const float*)d_in[8];
    const float* ew3   = (const float*)d_in[9];
    const float* eb3   = (const float*)d_in[10];
    const float* nw1   = (const float*)d_in[11];
    const float* nb1   = (const float*)d_in[12];
    const float* nw2   = (const float*)d_in[13];
    const float* nb2   = (const float*)d_in[14];
    const float* ow1   = (const float*)d_in[15];
    const float* ob1   = (const float*)d_in[16];
    const float* ow2   = (const float*)d_in[17];
    const float* ob2   = (const float*)d_in[18];
    const float* ow3   = (const float*)d_in[19];
    const float* ob3   = (const float*)d_in[20];

    char* ws = (char*)d_ws;
    int*   srcidx = (int*)ws;                                      // 5.24 MB
    float* h0   = (float*)(ws + (size_t)NTOT * KNN * sizeof(int)); // 4.19 MB
    float* h1   = h0 + (size_t)NTOT * HD;                          // 4.19 MB
    float* pre  = h1 + (size_t)NTOT * HD;                          // 25.2 MB
    float* gbuf = pre + (size_t)NTOT * PSTR;                       // 8.39 MB

    knn_kernel<<<NGRAPH * 8, 512, 0, stream>>>(pos, srcidx);
    embed_kernel<<<NTOT / 256, 256, 0, stream>>>(
        pos, pe_w1, pe_b1, pe_w2, pe_b2,
        ew1, eb1, nw1, nb1,            // layer-0 pre fold
        h0, pre);

    const int eblocks = (NTOT * KNN) / TPB;   // 4096
    for (int l = 0; l < 4; ++l) {
        const float* hin  = (l & 1) ? h1 : h0;
        float*       hout = (l & 1) ? h0 : h1;
        const int ln = (l < 3) ? l + 1 : l;   // next-layer weights (dummy for l=3)
        edge_kernel<<<eblocks, TPB, 0, stream>>>(
            pos, srcidx, pre,
            ew1 + (size_t)l * 37 * 32,
            ew2 + (size_t)l * 32 * 16, eb2 + (size_t)l * 16,
            ew3 + (size_t)l * 16 * 16, eb3 + (size_t)l * 16,
            gbuf);
        node_kernel<<<NTOT / EPB, 256, 0, stream>>>(
            hin, gbuf, pre,
            nw1 + (size_t)l * 48 * 32,
            nw2 + (size_t)l * 32 * 16, nb2 + (size_t)l * 16,
            hout,
            ew1 + (size_t)ln * 37 * 32, eb1 + (size_t)ln * 32,
            nw1 + (size_t)ln * 48 * 32, nb1 + (size_t)ln * 32,
            (l < 3) ? 1 : 0);
    }

    out_kernel<<<NTOT / 256, 256, 0, stream>>>(h0, ow1, ob1, ow2, ob2, ow3, ob3,
                                               (float*)d_out);
}